// Round 17
// baseline (61.638 us; speedup 1.0000x reference)
//
#include <hip/hip_runtime.h>

#define LN2F 0.6931471805599453f

// Problem constants (from setup_inputs: B=8, T=128, U=64, V=1024)
#define B_   8
#define T_   128
#define U_   64
#define U1_  65
#define V_   1024
#define ROWS_ (B_*T_*U1_)       // 66560
#define PROW_ 256               // packT row stride (dc slots, u32 each)
#define PACKT_B (64*PROW_)      // u32 per batch (rows u=1..64 -> idx u-1)
#define COL0N_ 224
#define NWAVES_ 8192            // persistent k1: 2048 blocks * 4 waves (8/CU, 32 waves/CU)
#define K1_BLOCKS_ 2048

typedef float f32x4 __attribute__((ext_vector_type(4)));

// lane l <- lane l-1; lane 0 <- 0.0 (DPP wave_shr:1, bound_ctrl=1). One VALU op.
__device__ __forceinline__ float shr1_f32(float x) {
  return __int_as_float(__builtin_amdgcn_update_dpp(
      0, __float_as_int(x), 0x138, 0xf, 0xf, true));
}

// Full-wave float max via DPP (VALU pipe only). R13-verified.
__device__ __forceinline__ float wave_fmax_dpp(float x) {
#define DPPM_(ctrl) { int t_ = __builtin_amdgcn_update_dpp(                  \
      __float_as_int(x), __float_as_int(x), (ctrl), 0xf, 0xf, false);        \
    x = fmaxf(x, __int_as_float(t_)); }
  DPPM_(0x111) DPPM_(0x112) DPPM_(0x114) DPPM_(0x118)
  DPPM_(0x142) DPPM_(0x143)
#undef DPPM_
  return __int_as_float(__builtin_amdgcn_readlane(__float_as_int(x), 63));
}

// Full-wave float sum via DPP (0-fill on invalid lanes = add identity).
__device__ __forceinline__ float wave_fsum_dpp(float x) {
#define DPPA_(ctrl) { int t_ = __builtin_amdgcn_update_dpp(                  \
      0, __float_as_int(x), (ctrl), 0xf, 0xf, true);                         \
    x += __int_as_float(t_); }
  DPPA_(0x111) DPPA_(0x112) DPPA_(0x114) DPPA_(0x118)
  DPPA_(0x142) DPPA_(0x143)
#undef DPPA_
  return __int_as_float(__builtin_amdgcn_readlane(__float_as_int(x), 63));
}

// wave-max of biased f32 exponents of (a, i0) via DPP reduce (R10-validated).
__device__ __forceinline__ int wave_max_bexp(float a, float i0) {
  int e  = (int)((__float_as_uint(a)  >> 23) & 0xffu);
  int e2 = (int)((__float_as_uint(i0) >> 23) & 0xffu);
  e = max(e, e2);
  int t;
  t = __builtin_amdgcn_update_dpp(e, e, 0x111, 0xf, 0xf, false); e = max(e, t);
  t = __builtin_amdgcn_update_dpp(e, e, 0x112, 0xf, 0xf, false); e = max(e, t);
  t = __builtin_amdgcn_update_dpp(e, e, 0x114, 0xf, 0xf, false); e = max(e, t);
  t = __builtin_amdgcn_update_dpp(e, e, 0x118, 0xf, 0xf, false); e = max(e, t);
  t = __builtin_amdgcn_update_dpp(e, e, 0x142, 0xf, 0xf, false); e = max(e, t);
  t = __builtin_amdgcn_update_dpp(e, e, 0x143, 0xf, 0xf, false); e = max(e, t);
  return __builtin_amdgcn_readlane(e, 63);
}

__device__ __forceinline__ unsigned short bf16_rn_(float f) {
  unsigned b = __float_as_uint(f);                 // f >= 0, finite
  return (unsigned short)((b + 0x7fffu + ((b >> 16) & 1u)) >> 16);
}

// ---------------------------------------------------------------------------
// K1: persistent-grid wave-per-row softmax with DPP reductions (R13-measured
//     ~40 us, at the cold-HBM floor). Emits LINEAR probs, bf16-packed,
//     LANE-MAJOR:
//       packT[b][u-1][t+u]   : lo16 = bf16(pll[t][u-1]), hi16 = bf16(pbl[t][u])
//         (lo written by row (t,u-1), hi by row (t,u): distinct bytes, no race)
//       col0[b][t+1]         = (pbl[t][0], pll[t][0])  (f32, DP side-chain)
// ---------------------------------------------------------------------------
__global__ __launch_bounds__(256) void k1_linsoftmax(
    const float* __restrict__ acts, const int* __restrict__ labels,
    const int* __restrict__ label_lens,
    unsigned int* __restrict__ packT, float2* __restrict__ col0,
    int* __restrict__ cnt) {
  const int lane = threadIdx.x & 63;
  const int wid  = blockIdx.x * 4 + (threadIdx.x >> 6);
  if (wid == 0 && lane == 0) *cnt = 0;             // k2's completion counter

  for (int row = wid; row < ROWS_; row += NWAVES_) {
    const int b   = row / (T_ * U1_);
    const int rem = row - b * (T_ * U1_);
    const int t   = rem / U1_;
    const int u   = rem - t * U1_;
    const float* __restrict__ p = acts + (size_t)row * V_;

    // hoisted label-path loads (lane 0 only)
    int ll_ = 0; float labv = 0.0f;
    if (lane == 0 && u < U_) {
      ll_  = label_lens[b];
      labv = p[labels[b * U_ + u]];                // in [1, V)
    }

    f32x4 v0 = *(const f32x4*)(p +   0 + lane * 4);
    f32x4 v1 = *(const f32x4*)(p + 256 + lane * 4);
    f32x4 v2 = *(const f32x4*)(p + 512 + lane * 4);
    f32x4 v3 = *(const f32x4*)(p + 768 + lane * 4);

    float ml = fmaxf(fmaxf(fmaxf(v0.x, v0.y), fmaxf(v0.z, v0.w)),
               fmaxf(fmaxf(fmaxf(v1.x, v1.y), fmaxf(v1.z, v1.w)),
               fmaxf(fmaxf(fmaxf(v2.x, v2.y), fmaxf(v2.z, v2.w)),
                     fmaxf(fmaxf(v3.x, v3.y), fmaxf(v3.z, v3.w)))));
    float m = wave_fmax_dpp(ml);

    float e00 = __expf(v0.x - m);                  // lane 0 holds exp(p[0]-m)
    float sl = e00          + __expf(v0.y - m) + __expf(v0.z - m) + __expf(v0.w - m)
             + __expf(v1.x - m) + __expf(v1.y - m) + __expf(v1.z - m) + __expf(v1.w - m)
             + __expf(v2.x - m) + __expf(v2.y - m) + __expf(v2.z - m) + __expf(v2.w - m)
             + __expf(v3.x - m) + __expf(v3.y - m) + __expf(v3.z - m) + __expf(v3.w - m);
    float s = wave_fsum_dpp(sl);

    if (lane == 0) {
      float rs = 1.0f / s;
      float pb = e00 * rs;                         // linear blank prob
      unsigned int* pkb = packT + (size_t)b * PACKT_B;
      if (u == 0) {
        float pl0 = __expf(labv - m) * rs;         // u=0 always unmasked (ll_ >= 32)
        col0[b * COL0N_ + (t + 1)] = make_float2(pb, pl0);
        ((unsigned short*)(pkb + 0 * PROW_ + (t + 1)))[0] = bf16_rn_(pl0);
      } else {
        ((unsigned short*)(pkb + (u - 1) * PROW_ + (t + u)))[1] = bf16_rn_(pb);
        if (u < U_) {
          float plv = (u < ll_) ? (__expf(labv - m) * rs) : 0.0f;
          ((unsigned short*)(pkb + u * PROW_ + (t + u + 1)))[0] = bf16_rn_(plv);
        }
      }
    }
  }
}

// ---------------------------------------------------------------------------
// K2: f32 probability-domain diagonal DP, bf16 lane-major operands, FULL
//     upfront prefetch: 13 bursts x 4 dwordx4 = 52 loads (<= 63 vmcnt cap)
//     issued before step 0 -> one cold-latency hit total (fix for the
//     R13/R16-measured latency bound: 16 scattered 8B loads per burst).
//     208 fully-unrolled steps; col0 side-chain staged in LDS.
// ---------------------------------------------------------------------------
__global__ __launch_bounds__(64, 1) void k2_alpha(
    const unsigned int* __restrict__ packT, const float2* __restrict__ col0,
    const int* __restrict__ act_lens, const int* __restrict__ label_lens,
    float* __restrict__ costs, int* __restrict__ cnt, float* __restrict__ out) {
  __shared__ float2 c0_s[COL0N_];
  const int b = (int)blockIdx.x;
  const int l = (int)threadIdx.x;                  // 0..63

  {  // stage col0 -> LDS; c0_s[0]=(1,0) (mult identity, no inject); tail zero
    const float2* src = col0 + (size_t)b * COL0N_;
    #pragma unroll
    for (int k = 0; k < 4; ++k) {
      int i = k * 64 + l;
      if (i < COL0N_) {
        float2 v = src[i];
        float2 z = make_float2(0.0f, 0.0f);
        c0_s[i] = (i == 0) ? make_float2(1.0f, 0.0f)
                           : ((i <= T_) ? v : z);
      }
    }
  }
  // single wave: compiler-ordered counters; no barrier needed

  const int tl = act_lens[b] - 1;                  // in [63,127]
  const int ll = label_lens[b];                    // in [32,64]
  const int u  = l + 1;
  const int dccap = (u == ll) ? (tl + u) : -1;     // capture step (95..191) or never

  const uint4* __restrict__ rp =
      (const uint4*)(packT + (size_t)b * PACKT_B + (size_t)l * PROW_);

  // ---- prefetch the ENTIRE DP: bursts 0..12, dc = 16*i .. 16*i+15 ----
#define PF_(I) const uint4 q##I##_0 = rp[4*(I)+0], q##I##_1 = rp[4*(I)+1], \
                           q##I##_2 = rp[4*(I)+2], q##I##_3 = rp[4*(I)+3];
  PF_(0) PF_(1) PF_(2) PF_(3) PF_(4) PF_(5) PF_(6)
  PF_(7) PF_(8) PF_(9) PF_(10) PF_(11) PF_(12)
#undef PF_

  float a = 0.0f;
  float i0 = (l == 0) ? 1.0f : 0.0f;               // alpha0 side-chain (lane 0)
  float fin = 0.0f, pbc = 0.0f;
  int   S = 0, Ecap = 0;

#define RENORM_() do {                                                   \
    int eS_ = wave_max_bexp(a, i0);                                      \
    int sh_ = min(167 - eS_, 126);     /* target biased exp 167 = 2^40 */\
    S += sh_;                                                            \
    float sc_ = ldexpf(1.0f, sh_);                                       \
    a *= sc_; i0 *= sc_;                                                 \
  } while (0);

#define STEP_(DC, VV, CC) do {                                           \
    const unsigned int v_ = (VV);                                        \
    float shin = shr1_f32(a);                                            \
    float inj  = i0 * (CC).y;                                            \
    float anew = fmaf(a, pbc,                                            \
                      fmaf(shin, __uint_as_float(v_ << 16), inj));       \
    bool valid = (u <= (DC)) && (u + T_ > (DC));   /* folds per DC */    \
    a = valid ? anew : 0.0f;                                             \
    bool cap = (dccap == (DC));                                          \
    fin  = cap ? a : fin;                                                \
    Ecap = cap ? S : Ecap;                                               \
    i0 *= (CC).x;                                                        \
    pbc = __uint_as_float(v_ & 0xffff0000u);                             \
  } while (0);

#define BURST_(DC0, Q0, Q1, Q2, Q3, C)                                   \
  RENORM_()                                                              \
  STEP_((DC0)+0,  (Q0).x, (C)[0])  STEP_((DC0)+1,  (Q0).y, (C)[1])       \
  STEP_((DC0)+2,  (Q0).z, (C)[2])  STEP_((DC0)+3,  (Q0).w, (C)[3])       \
  STEP_((DC0)+4,  (Q1).x, (C)[4])  STEP_((DC0)+5,  (Q1).y, (C)[5])       \
  STEP_((DC0)+6,  (Q1).z, (C)[6])  STEP_((DC0)+7,  (Q1).w, (C)[7])       \
  RENORM_()                                                              \
  STEP_((DC0)+8,  (Q2).x, (C)[8])  STEP_((DC0)+9,  (Q2).y, (C)[9])       \
  STEP_((DC0)+10, (Q2).z, (C)[10]) STEP_((DC0)+11, (Q2).w, (C)[11])      \
  STEP_((DC0)+12, (Q3).x, (C)[12]) STEP_((DC0)+13, (Q3).y, (C)[13])      \
  STEP_((DC0)+14, (Q3).z, (C)[14]) STEP_((DC0)+15, (Q3).w, (C)[15])

#define LOADC_(C, DC0) { _Pragma("unroll")                               \
    for (int j_ = 0; j_ < 16; ++j_) (C)[j_] = c0_s[(DC0) + j_]; }

  float2 cA[16], cB[16];
  LOADC_(cA, 0); LOADC_(cB, 16);
  BURST_(0,   q0_0,  q0_1,  q0_2,  q0_3,  cA) LOADC_(cA, 32);
  BURST_(16,  q1_0,  q1_1,  q1_2,  q1_3,  cB) LOADC_(cB, 48);
  BURST_(32,  q2_0,  q2_1,  q2_2,  q2_3,  cA) LOADC_(cA, 64);
  BURST_(48,  q3_0,  q3_1,  q3_2,  q3_3,  cB) LOADC_(cB, 80);
  BURST_(64,  q4_0,  q4_1,  q4_2,  q4_3,  cA) LOADC_(cA, 96);
  BURST_(80,  q5_0,  q5_1,  q5_2,  q5_3,  cB) LOADC_(cB, 112);
  BURST_(96,  q6_0,  q6_1,  q6_2,  q6_3,  cA) LOADC_(cA, 128);
  BURST_(112, q7_0,  q7_1,  q7_2,  q7_3,  cB) LOADC_(cB, 144);
  BURST_(128, q8_0,  q8_1,  q8_2,  q8_3,  cA) LOADC_(cA, 160);
  BURST_(144, q9_0,  q9_1,  q9_2,  q9_3,  cB) LOADC_(cB, 176);
  BURST_(160, q10_0, q10_1, q10_2, q10_3, cA) LOADC_(cA, 192);
  BURST_(176, q11_0, q11_1, q11_2, q11_3, cB)
  BURST_(192, q12_0, q12_1, q12_2, q12_3, cA)
#undef BURST_
#undef STEP_
#undef RENORM_
#undef LOADC_

  if (u == ll) {                                   // exactly one lane (ll in [32,64])
    unsigned int vlast = packT[(size_t)b * PACKT_B + (size_t)(ll - 1) * PROW_ + (tl + ll)];
    float pblast = __uint_as_float(vlast & 0xffff0000u);  // bf16(pbl[tl][ll])
    float lg = __log2f(fin) - (float)Ecap + __log2f(pblast);
    costs[b] = -lg * LN2F;
  }

  // last block to arrive sums the 8 costs (deterministic: single writer)
  __threadfence();
  if (l == 0) {
    int old = atomicAdd(cnt, 1);
    if (old == B_ - 1) {
      __threadfence();
      volatile const float* vc = costs;
      float s = 0.0f;
      #pragma unroll
      for (int i = 0; i < B_; ++i) s += vc[i];
      out[0] = s;
    }
  }
}

extern "C" void kernel_launch(void* const* d_in, const int* in_sizes, int n_in,
                              void* d_out, int out_size, void* d_ws, size_t ws_size,
                              hipStream_t stream) {
  const float* acts       = (const float*)d_in[0];
  const int*   labels     = (const int*)d_in[1];
  const int*   act_lens   = (const int*)d_in[2];
  const int*   label_lens = (const int*)d_in[3];

  unsigned int* packT = (unsigned int*)d_ws;         // B * 64*256 u32 = 512 KB
  float2* col0  = (float2*)(packT + (size_t)B_ * PACKT_B);  // B * 224 float2
  float*  costs = (float*)(col0 + (size_t)B_ * COL0N_);
  int*    cnt   = (int*)(costs + B_);                // 1 int

  k1_linsoftmax<<<K1_BLOCKS_, 256, 0, stream>>>(acts, labels, label_lens, packT, col0, cnt);
  k2_alpha<<<B_, 64, 0, stream>>>(packT, col0, act_lens, label_lens, costs, cnt, (float*)d_out);
}

// Round 18
// 57.542 us; speedup vs baseline: 1.0712x; 1.0712x over previous
//
#include <hip/hip_runtime.h>

#define LN2F 0.6931471805599453f

// Problem constants (from setup_inputs: B=8, T=128, U=64, V=1024)
#define B_   8
#define T_   128
#define U_   64
#define U1_  65
#define V_   1024
#define ROWS_ (B_*T_*U1_)       // 66560
#define NDIAG_ 224              // diag index g=t+u in [0,192]; padded
#define DS_    66               // float2 slots per diagonal (i = u in [1,64] used)
#define PACKB_ (NDIAG_*DS_)     // float2 per batch = 14784
#define COL0N_ 224
#define NWAVES_ 8192            // persistent k1: 2048 blocks * 4 waves (8/CU, 32 waves/CU)
#define K1_BLOCKS_ 2048

typedef float f32x4 __attribute__((ext_vector_type(4)));

// lane l <- lane l-1; lane 0 <- 0.0 (DPP wave_shr:1, bound_ctrl=1). One VALU op.
__device__ __forceinline__ float shr1_f32(float x) {
  return __int_as_float(__builtin_amdgcn_update_dpp(
      0, __float_as_int(x), 0x138, 0xf, 0xf, true));
}

// Full-wave float max via DPP (VALU pipe only; no DS traffic). R13-verified.
__device__ __forceinline__ float wave_fmax_dpp(float x) {
#define DPPM_(ctrl) { int t_ = __builtin_amdgcn_update_dpp(                  \
      __float_as_int(x), __float_as_int(x), (ctrl), 0xf, 0xf, false);        \
    x = fmaxf(x, __int_as_float(t_)); }
  DPPM_(0x111) DPPM_(0x112) DPPM_(0x114) DPPM_(0x118)   // row_shr 1,2,4,8
  DPPM_(0x142) DPPM_(0x143)                             // row_bcast 15,31
#undef DPPM_
  return __int_as_float(__builtin_amdgcn_readlane(__float_as_int(x), 63));
}

// Full-wave float sum via DPP (0-fill on invalid lanes = add identity).
__device__ __forceinline__ float wave_fsum_dpp(float x) {
#define DPPA_(ctrl) { int t_ = __builtin_amdgcn_update_dpp(                  \
      0, __float_as_int(x), (ctrl), 0xf, 0xf, true);                         \
    x += __int_as_float(t_); }
  DPPA_(0x111) DPPA_(0x112) DPPA_(0x114) DPPA_(0x118)
  DPPA_(0x142) DPPA_(0x143)
#undef DPPA_
  return __int_as_float(__builtin_amdgcn_readlane(__float_as_int(x), 63));
}

// wave-max of biased f32 exponents of (a, i0) via DPP reduce (R10-validated).
__device__ __forceinline__ int wave_max_bexp(float a, float i0) {
  int e  = (int)((__float_as_uint(a)  >> 23) & 0xffu);
  int e2 = (int)((__float_as_uint(i0) >> 23) & 0xffu);
  e = max(e, e2);
  int t;
  t = __builtin_amdgcn_update_dpp(e, e, 0x111, 0xf, 0xf, false); e = max(e, t);
  t = __builtin_amdgcn_update_dpp(e, e, 0x112, 0xf, 0xf, false); e = max(e, t);
  t = __builtin_amdgcn_update_dpp(e, e, 0x114, 0xf, 0xf, false); e = max(e, t);
  t = __builtin_amdgcn_update_dpp(e, e, 0x118, 0xf, 0xf, false); e = max(e, t);
  t = __builtin_amdgcn_update_dpp(e, e, 0x142, 0xf, 0xf, false); e = max(e, t);
  t = __builtin_amdgcn_update_dpp(e, e, 0x143, 0xf, 0xf, false); e = max(e, t);
  return __builtin_amdgcn_readlane(e, 63);
}

// ---------------------------------------------------------------------------
// K1: persistent-grid wave-per-row softmax (2048 blocks, 32 waves/CU) with
//     DPP reductions (R13-measured: ~40 us, at the cold-HBM floor). Emits
//     LINEAR probs in diagonal-major layout:
//       pk[b][t+u][u] = (.x = pll[t][u-1], .y = pbl[t][u])
//       col0[b][t+1]  = (.x = pbl[t][0],   .y = pll[t][0])
// ---------------------------------------------------------------------------
__global__ __launch_bounds__(256) void k1_linsoftmax(
    const float* __restrict__ acts, const int* __restrict__ labels,
    const int* __restrict__ label_lens,
    float2* __restrict__ pack, float2* __restrict__ col0, int* __restrict__ cnt) {
  const int lane = threadIdx.x & 63;
  const int wid  = blockIdx.x * 4 + (threadIdx.x >> 6);
  if (wid == 0 && lane == 0) *cnt = 0;             // k2's completion counter

  for (int row = wid; row < ROWS_; row += NWAVES_) {
    const int b   = row / (T_ * U1_);
    const int rem = row - b * (T_ * U1_);
    const int t   = rem / U1_;
    const int u   = rem - t * U1_;
    const float* __restrict__ p = acts + (size_t)row * V_;

    // hoisted label-path loads (lane 0 only)
    int ll_ = 0; float labv = 0.0f;
    if (lane == 0 && u < U_) {
      ll_  = label_lens[b];
      labv = p[labels[b * U_ + u]];                // in [1, V)
    }

    f32x4 v0 = *(const f32x4*)(p +   0 + lane * 4);
    f32x4 v1 = *(const f32x4*)(p + 256 + lane * 4);
    f32x4 v2 = *(const f32x4*)(p + 512 + lane * 4);
    f32x4 v3 = *(const f32x4*)(p + 768 + lane * 4);

    float ml = fmaxf(fmaxf(fmaxf(v0.x, v0.y), fmaxf(v0.z, v0.w)),
               fmaxf(fmaxf(fmaxf(v1.x, v1.y), fmaxf(v1.z, v1.w)),
               fmaxf(fmaxf(fmaxf(v2.x, v2.y), fmaxf(v2.z, v2.w)),
                     fmaxf(fmaxf(v3.x, v3.y), fmaxf(v3.z, v3.w)))));
    float m = wave_fmax_dpp(ml);

    float e00 = __expf(v0.x - m);                  // lane 0 holds exp(p[0]-m)
    float sl = e00          + __expf(v0.y - m) + __expf(v0.z - m) + __expf(v0.w - m)
             + __expf(v1.x - m) + __expf(v1.y - m) + __expf(v1.z - m) + __expf(v1.w - m)
             + __expf(v2.x - m) + __expf(v2.y - m) + __expf(v2.z - m) + __expf(v2.w - m)
             + __expf(v3.x - m) + __expf(v3.y - m) + __expf(v3.z - m) + __expf(v3.w - m);
    float s = wave_fsum_dpp(sl);

    if (lane == 0) {
      float rs = 1.0f / s;
      float pb = e00 * rs;                         // linear blank prob
      float2* pk = pack + (size_t)b * PACKB_;
      if (u == 0) {
        float pl0 = __expf(labv - m) * rs;         // u=0 < ll_ always (ll_ >= 32)
        col0[b * COL0N_ + (t + 1)] = make_float2(pb, pl0);
        pk[(size_t)(t + 1) * DS_ + 1].x = pl0;
      } else {
        pk[(size_t)(t + u) * DS_ + u].y = pb;
        if (u < U_) {
          float plv = (u < ll_) ? (__expf(labv - m) * rs) : 0.0f;
          pk[(size_t)(t + u + 1) * DS_ + (u + 1)].x = plv;
        }
      }
    }
  }
}

// ---------------------------------------------------------------------------
// K2: f32 probability-domain diagonal DP with deep prefetch (R16-measured
//     best: ~14.8 us cold). col0 lives in LDS (lgkm counter; tail pre-
//     zeroed), so each 16-step burst is only 16 vmem ops; 4 named buffer
//     sets give lookahead-3 (48 steps of compute cover, 48 outstanding
//     vmem <= 63 cap).
// ---------------------------------------------------------------------------
__global__ __launch_bounds__(64) void k2_alpha(
    const float2* __restrict__ pack, const float2* __restrict__ col0,
    const int* __restrict__ act_lens, const int* __restrict__ label_lens,
    float* __restrict__ costs, int* __restrict__ cnt, float* __restrict__ out) {
  __shared__ float2 c0_s[COL0N_];
  const int b  = (int)blockIdx.x;
  const int l  = (int)threadIdx.x;                 // 0..63

  {  // stage col0 into LDS; zero unwritten tail (valid indices are 1..128)
    const float2* src = col0 + (size_t)b * COL0N_;
    #pragma unroll
    for (int k = 0; k < 4; ++k) {
      int i = k * 64 + l;                          // 0..255; COL0N_=224
      if (i < COL0N_) {
        float2 v = src[i];
        bool ok = (i >= 1) && (i <= T_);
        c0_s[i] = ok ? v : make_float2(0.0f, 0.0f);
      }
    }
  }
  // single wave: no barrier needed; compiler orders vm/ds counters

  const int tl = act_lens[b] - 1;                  // in [63,127]
  const int ll = label_lens[b];                    // in [32,64]
  const int u  = l + 1;
  const int tcap = (u == ll) ? tl : 0x7fffffff;    // capture when t_ == tcap

  const float2* __restrict__ pku = pack + (size_t)b * PACKB_ + u;   // +DS_ per diag

  float a = 0.0f;
  float i0 = (l == 0) ? 1.0f : 0.0f;               // alpha0 side-chain (lane 0)
  float fin = 0.0f, pbc = 0.0f;
  int   S = 0, Ecap = 0;
  int   t_ = -u;                                   // becomes dc-u after ++ in step

  float2 pA[16], pB[16], pC[16], pD[16];
  float2 cA[16], cB[16], cC[16], cD[16];

#define LOADP(P, C, DB) do {                                             \
    const float2* q_ = pku + (size_t)(DB) * DS_;                         \
    _Pragma("unroll")                                                    \
    for (int j = 0; j < 16; ++j) (P)[j] = q_[(size_t)j * DS_];           \
    _Pragma("unroll")                                                    \
    for (int j = 0; j < 16; ++j) (C)[j] = c0_s[(DB) + j];                \
  } while (0)

#define RENORM() do {                                                    \
    int eS_ = wave_max_bexp(a, i0);                                      \
    int sh_ = min(167 - eS_, 126);     /* target biased exp 167 = 2^40 */\
    S += sh_;                                                            \
    float sc_ = ldexpf(1.0f, sh_);                                       \
    a *= sc_; i0 *= sc_;                                                 \
  } while (0)

#define COMPUTE8(P, C, JO) do {                                          \
    _Pragma("unroll")                                                    \
    for (int jj = 0; jj < 8; ++jj) {                                     \
      const int j = (JO) + jj;                                           \
      t_ += 1;                                                           \
      float shin = shr1_f32(a);                                          \
      float inj  = i0 * (C)[j].y;                                        \
      float anew = fmaf(a, pbc, fmaf(shin, (P)[j].x, inj));              \
      bool valid = ((unsigned)t_ < (unsigned)T_);                        \
      a = valid ? anew : 0.0f;            /* kills pad garbage/NaN */    \
      bool cap = (t_ == tcap);                                           \
      fin  = cap ? a : fin;                                              \
      Ecap = cap ? S : Ecap;                                             \
      i0 *= (C)[j].x;                                                    \
      pbc = (P)[j].y;                                                    \
    }                                                                    \
  } while (0)

  // prologue: 4 blocks in flight (dc = 1..64)
  LOADP(pA, cA, 1);
  LOADP(pB, cB, 17);
  LOADP(pC, cC, 33);
  LOADP(pD, cD, 49);

  #pragma unroll 1
  for (int it4 = 0; it4 < 3; ++it4) {              // 4 blocks of 16 steps per iter
    if (it4 > 0) RENORM();
    COMPUTE8(pA, cA, 0);
    RENORM();
    COMPUTE8(pA, cA, 8);
    if (it4 < 2) LOADP(pA, cA, 64 * it4 + 65);     // block +4 (lookahead 3)

    RENORM();
    COMPUTE8(pB, cB, 0);
    RENORM();
    COMPUTE8(pB, cB, 8);
    if (it4 < 2) LOADP(pB, cB, 64 * it4 + 81);

    RENORM();
    COMPUTE8(pC, cC, 0);
    RENORM();
    COMPUTE8(pC, cC, 8);
    if (it4 < 2) LOADP(pC, cC, 64 * it4 + 97);

    RENORM();
    COMPUTE8(pD, cD, 0);
    RENORM();
    COMPUTE8(pD, cD, 8);
    if (it4 < 2) LOADP(pD, cD, 64 * it4 + 113);
  }
#undef LOADP
#undef RENORM
#undef COMPUTE8

  if (u == ll) {                                   // exactly one lane (ll in [32,64])
    float pblast = pack[(size_t)b * PACKB_ + (size_t)(tl + ll) * DS_ + ll].y;  // pbl[tl][ll]
    float lg = __log2f(fin) - (float)Ecap + __log2f(pblast);
    costs[b] = -lg * LN2F;
  }

  // last block to arrive sums the 8 costs (deterministic: single writer)
  __threadfence();
  if (l == 0) {
    int old = atomicAdd(cnt, 1);
    if (old == B_ - 1) {
      __threadfence();
      volatile const float* vc = costs;
      float s = 0.0f;
      #pragma unroll
      for (int i = 0; i < B_; ++i) s += vc[i];
      out[0] = s;
    }
  }
}

extern "C" void kernel_launch(void* const* d_in, const int* in_sizes, int n_in,
                              void* d_out, int out_size, void* d_ws, size_t ws_size,
                              hipStream_t stream) {
  const float* acts       = (const float*)d_in[0];
  const int*   labels     = (const int*)d_in[1];
  const int*   act_lens   = (const int*)d_in[2];
  const int*   label_lens = (const int*)d_in[3];

  float2* pack  = (float2*)d_ws;                     // B * 224*66 float2 = 946 KB
  float2* col0  = pack + (size_t)B_ * PACKB_;        // B * 224 float2
  float*  costs = (float*)(col0 + (size_t)B_ * COL0N_);
  int*    cnt   = (int*)(costs + B_);                // 1 int

  k1_linsoftmax<<<K1_BLOCKS_, 256, 0, stream>>>(acts, labels, label_lens, pack, col0, cnt);
  k2_alpha<<<B_, 64, 0, stream>>>(pack, col0, act_lens, label_lens, costs, cnt, (float*)d_out);
}